// Round 1
// baseline (27.633 us; speedup 1.0000x reference)
//
#include <hip/hip_runtime.h>

// AGCBlock collapses: log_softmax over singleton axis == 0, so context == 0,
// t == b1 (constant), term == relu(LN(b1))*w2^T + b2 is ONE constant C-vector.
// out_p = patches + term[c]; fold(unfold(x))/counts == x (all pixels covered,
// every overlapping patch holds the identical pixel value). Hence:
//     out[0, c, h, w] = x[0, c, h, w] + term[c]
// Memory-bound elementwise add: 64 MiB read + 64 MiB write.

#define IMGHW (512 * 512)   // 262144
#define CCH   64
#define PCH   32
#define LN_EPS 1e-5f

__global__ __launch_bounds__(256) void agc_fused_kernel(
    const float* __restrict__ x,
    const float* __restrict__ b1,
    const float* __restrict__ gamma,
    const float* __restrict__ beta,
    const float* __restrict__ w2,   // [C, P] row-major
    const float* __restrict__ b2,
    float* __restrict__ out)
{
    __shared__ float term[CCH];
    const int tid = threadIdx.x;

    // Threads 0..63 compute the constant per-channel term (inputs are 128 B
    // each -> L1/L2 resident; redundant per-block compute is free vs a second
    // launch).
    if (tid < CCH) {
        float mu = 0.f;
        #pragma unroll
        for (int p = 0; p < PCH; ++p) mu += b1[p];
        mu *= (1.0f / PCH);
        float var = 0.f;
        #pragma unroll
        for (int p = 0; p < PCH; ++p) { float d = b1[p] - mu; var += d * d; }
        var *= (1.0f / PCH);
        const float inv = rsqrtf(var + LN_EPS);
        float acc = b2[tid];
        #pragma unroll
        for (int p = 0; p < PCH; ++p) {
            float t = (b1[p] - mu) * inv * gamma[p] + beta[p];
            t = fmaxf(t, 0.f);
            acc = fmaf(t, w2[tid * PCH + p], acc);
        }
        term[tid] = acc;
    }
    __syncthreads();

    // Elementwise: out = x + term[channel], vectorized float4.
    // IMGHW/4 = 65536 float4 per channel -> channel = i >> 16.
    const float4* __restrict__ x4 = (const float4*)x;
    float4* __restrict__ o4 = (float4*)out;
    const int total4 = CCH * IMGHW / 4;   // 4,194,304
    const int stride = gridDim.x * blockDim.x;
    for (int i = blockIdx.x * blockDim.x + tid; i < total4; i += stride) {
        const float tv = term[i >> 16];
        float4 v = x4[i];
        v.x += tv; v.y += tv; v.z += tv; v.w += tv;
        o4[i] = v;
    }
}

extern "C" void kernel_launch(void* const* d_in, const int* in_sizes, int n_in,
                              void* d_out, int out_size, void* d_ws, size_t ws_size,
                              hipStream_t stream) {
    // setup_inputs order: 0:x 1:w_mask 2:b_mask 3:w1 4:b1 5:gamma 6:beta 7:w2 8:b2
    const float* x     = (const float*)d_in[0];
    const float* b1    = (const float*)d_in[4];
    const float* gamma = (const float*)d_in[5];
    const float* beta  = (const float*)d_in[6];
    const float* w2    = (const float*)d_in[7];
    const float* b2    = (const float*)d_in[8];
    float* out = (float*)d_out;

    const int blocks = 2048;  // 256 CUs x 8 blocks; grid-stride covers 4,194,304 float4
    agc_fused_kernel<<<blocks, 256, 0, stream>>>(x, b1, gamma, beta, w2, b2, out);
}

// Round 3
// 26.288 us; speedup vs baseline: 1.0512x; 1.0512x over previous
//
#include <hip/hip_runtime.h>

// AGCBlock collapses: log_softmax over singleton axis == 0 -> context == 0 ->
// t == b1 (constant) -> term = relu(LN(b1))*w2^T + b2 is ONE constant C-vector.
// fold(unfold(x))/counts == x, so out[0,c,h,w] = x[0,c,h,w] + term[c].
// Pure streaming add: 64 MiB read + 64 MiB write.

#define IMGHW (512 * 512)   // 262144
#define CCH   64
#define PCH   32
#define LN_EPS 1e-5f

typedef float v4f __attribute__((ext_vector_type(4)));

// total float4 elements = CCH * IMGHW / 4 = 4,194,304
// each thread: 2 float4 -> 512 per block -> 8192 blocks exactly.
#define TOTAL4   (CCH * IMGHW / 4)
#define PER_BLK  512
#define NBLOCKS  (TOTAL4 / PER_BLK)   // 8192

__global__ __launch_bounds__(256) void agc_fused_kernel(
    const float* __restrict__ x,
    const float* __restrict__ b1,
    const float* __restrict__ gamma,
    const float* __restrict__ beta,
    const float* __restrict__ w2,   // [C, P] row-major
    const float* __restrict__ b2,
    float* __restrict__ out)
{
    __shared__ float term[CCH];
    const int tid = threadIdx.x;

    // Threads 0..63 compute the constant per-channel term (tiny, L2-resident).
    if (tid < CCH) {
        float mu = 0.f;
        #pragma unroll
        for (int p = 0; p < PCH; ++p) mu += b1[p];
        mu *= (1.0f / PCH);
        float var = 0.f;
        #pragma unroll
        for (int p = 0; p < PCH; ++p) { float d = b1[p] - mu; var += d * d; }
        var *= (1.0f / PCH);
        const float inv = rsqrtf(var + LN_EPS);
        float acc = b2[tid];
        #pragma unroll
        for (int p = 0; p < PCH; ++p) {
            float t = (b1[p] - mu) * inv * gamma[p] + beta[p];
            t = fmaxf(t, 0.f);
            acc = fmaf(t, w2[tid * PCH + p], acc);
        }
        term[tid] = acc;
    }
    __syncthreads();

    const v4f* __restrict__ x4 = (const v4f*)x;
    v4f* __restrict__ o4 = (v4f*)out;

    // Two independent float4 per thread, both issued before either use.
    const int i0 = blockIdx.x * PER_BLK + tid;
    const int i1 = i0 + 256;

    v4f v0 = x4[i0];
    v4f v1 = x4[i1];
    const float t0 = term[i0 >> 16];   // 65536 float4 per channel
    const float t1 = term[i1 >> 16];
    v0 += t0;
    v1 += t1;
    // Non-temporal stores: out is never re-read; keep x resident in L3.
    __builtin_nontemporal_store(v0, &o4[i0]);
    __builtin_nontemporal_store(v1, &o4[i1]);
}

extern "C" void kernel_launch(void* const* d_in, const int* in_sizes, int n_in,
                              void* d_out, int out_size, void* d_ws, size_t ws_size,
                              hipStream_t stream) {
    // setup_inputs order: 0:x 1:w_mask 2:b_mask 3:w1 4:b1 5:gamma 6:beta 7:w2 8:b2
    const float* x     = (const float*)d_in[0];
    const float* b1    = (const float*)d_in[4];
    const float* gamma = (const float*)d_in[5];
    const float* beta  = (const float*)d_in[6];
    const float* w2    = (const float*)d_in[7];
    const float* b2    = (const float*)d_in[8];
    float* out = (float*)d_out;

    agc_fused_kernel<<<NBLOCKS, 256, 0, stream>>>(x, b1, gamma, beta, w2, b2, out);
}